// Round 3
// baseline (53.105 us; speedup 1.0000x reference)
//
#include <hip/hip_runtime.h>

// Problem constants (from reference): x[B,S,H], W*[H,H], b*[H], out[B,H]
#define BB 32
#define SS 1024
#define HH 256
#define SPLITS 16
#define ROWS (SS / SPLITS)  // 64 rows per worker block

// ---------------------------------------------------------------------------
// Math note: reference softmaxes over the QUERY axis (axis=1), so
// sum_q attn[b,q,k] == 1 for every (b,k). Then sum_q context = sum_k v.
// Hence out[b,h] = sum_h' Wv[h,h'] * (sum_s x[b,s,h']) + S * bv[h], exactly.
// Only x needs to be read (32 MB); Wq/bq/Wk/bk are provably unused.
//
// Fused structure: 512 blocks (16 per batch). Each sums its 64 rows of x,
// writes a partial, fences, and bumps the batch's arrival counter. The 16th
// arriver for a batch reduces the 16 partials (L2-hot) and does the matvec
// + bias for that batch — no second kernel, phase 2 overlaps phase 1.
// Counters are zeroed by a 128 B hipMemsetAsync each call (poison-proof).
// Atomics only ELECT the finisher; summation order is fixed -> deterministic.
// ---------------------------------------------------------------------------

__global__ __launch_bounds__(256) void fused_attn_kernel(
    const float* __restrict__ x, const float* __restrict__ Wv,
    const float* __restrict__ bv, float* __restrict__ out,
    float* __restrict__ partials, unsigned int* __restrict__ counters) {
    const int blk   = blockIdx.x;
    const int b     = blk >> 4;   // batch
    const int split = blk & 15;   // which 64-row slice
    const int tid   = threadIdx.x;
    const int h4    = tid & 63;   // float4 column group (64 cover 256 floats)
    const int ph    = tid >> 6;   // 0..3 row/split phase

    // ---- Phase 1: partial column sum of 64 rows of x[b] ----
    const float4* xb = reinterpret_cast<const float4*>(
        x + (size_t)b * SS * HH + (size_t)split * ROWS * HH);

    float4 acc = make_float4(0.f, 0.f, 0.f, 0.f);
    #pragma unroll
    for (int r = ph; r < ROWS; r += 4) {
        float4 v = xb[(size_t)r * (HH / 4) + h4];
        acc.x += v.x; acc.y += v.y; acc.z += v.z; acc.w += v.w;
    }

    __shared__ float4 lds[256];
    lds[tid] = acc;
    __syncthreads();
    if (tid < 64) {
        float4 a0 = lds[tid];
        float4 a1 = lds[tid + 64];
        float4 a2 = lds[tid + 128];
        float4 a3 = lds[tid + 192];
        float4 r;
        r.x = (a0.x + a1.x) + (a2.x + a3.x);
        r.y = (a0.y + a1.y) + (a2.y + a3.y);
        r.z = (a0.z + a1.z) + (a2.z + a3.z);
        r.w = (a0.w + a1.w) + (a2.w + a3.w);
        reinterpret_cast<float4*>(
            partials + ((size_t)b * SPLITS + split) * HH)[h4] = r;
        __threadfence();  // release our partial device-wide (per storing thread)
    }
    __syncthreads();

    // ---- Arrival: elect the finisher for this batch ----
    __shared__ unsigned int ticket;
    if (tid == 0) ticket = atomicAdd(&counters[b], 1u);
    __syncthreads();
    if (ticket != SPLITS - 1) return;  // not last -> done

    // ---- Phase 2 (one block per batch): reduce partials + matvec ----
    __threadfence();  // acquire side: see all 16 partials

    const float4* pb = reinterpret_cast<const float4*>(
        partials + (size_t)b * SPLITS * HH);
    float4 a4 = make_float4(0.f, 0.f, 0.f, 0.f);
    #pragma unroll
    for (int c = ph; c < SPLITS; c += 4) {
        float4 v = pb[(size_t)c * (HH / 4) + h4];
        a4.x += v.x; a4.y += v.y; a4.z += v.z; a4.w += v.w;
    }
    __syncthreads();  // lds[] reuse: phase-1 readers are done (same block)
    lds[tid] = a4;
    __syncthreads();

    __shared__ float xsum[HH];
    if (tid < 64) {
        float4 a0 = lds[tid];
        float4 a1 = lds[tid + 64];
        float4 a2 = lds[tid + 128];
        float4 a3 = lds[tid + 192];
        float4 r;
        r.x = (a0.x + a1.x) + (a2.x + a3.x);
        r.y = (a0.y + a1.y) + (a2.y + a3.y);
        r.z = (a0.z + a1.z) + (a2.z + a3.z);
        r.w = (a0.w + a1.w) + (a2.w + a3.w);
        reinterpret_cast<float4*>(xsum)[tid] = r;
    }
    __syncthreads();

    const int h = tid;
    const float4* wrow = reinterpret_cast<const float4*>(Wv + (size_t)h * HH);
    const float4* xs   = reinterpret_cast<const float4*>(xsum);
    float o = (float)SS * bv[h];
    #pragma unroll 8
    for (int i = 0; i < HH / 4; ++i) {
        float4 w  = wrow[i];
        float4 xv = xs[i];
        o += w.x * xv.x + w.y * xv.y + w.z * xv.z + w.w * xv.w;
    }
    out[(size_t)b * HH + h] = o;
}

extern "C" void kernel_launch(void* const* d_in, const int* in_sizes, int n_in,
                              void* d_out, int out_size, void* d_ws, size_t ws_size,
                              hipStream_t stream) {
    // setup_inputs order: x, Wq, bq, Wk, bk, Wv, bv
    const float* x  = (const float*)d_in[0];
    const float* Wv = (const float*)d_in[5];
    const float* bv = (const float*)d_in[6];
    float* out = (float*)d_out;

    // ws layout: partials [BB][SPLITS][HH] f32 (512 KB), then counters [BB] u32.
    float* partials = (float*)d_ws;
    unsigned int* counters =
        (unsigned int*)((char*)d_ws + (size_t)BB * SPLITS * HH * sizeof(float));

    // Counters must be 0 at kernel start every call (ws is poisoned to 0xAA
    // once and never restored) — zero them with a tiny capturable memset.
    hipMemsetAsync(counters, 0, BB * sizeof(unsigned int), stream);

    fused_attn_kernel<<<BB * SPLITS, 256, 0, stream>>>(
        x, Wv, bv, out, partials, counters);
}

// Round 4
// 30.102 us; speedup vs baseline: 1.7642x; 1.7642x over previous
//
#include <hip/hip_runtime.h>

// Problem constants (from reference): x[B,S,H], W*[H,H], b*[H], out[B,H]
#define BB 32
#define SS 1024
#define HH 256
#define SPLITS 16
#define ROWS (SS / SPLITS)  // 64 rows per block

// ---------------------------------------------------------------------------
// Math note: reference softmaxes over the QUERY axis (axis=1), so
// sum_q attn[b,q,k] == 1 for every (b,k). Then sum_q context = sum_k v.
// Hence out[b,h] = sum_h' Wv[h,h'] * (sum_s x[b,s,h']) + S * bv[h], exactly.
// Only x needs to be read (32 MB); Wq/bq/Wk/bk are provably unused.
//
// Fusion via linearity: out[b,:] = sum_split Wv . xpart[b,split,:] + S*bv.
// Each block (b,split) sums its 64 rows, does the full matvec on its own
// partial (Wv is 256 KB -> L2-hot everywhere), and atomicAdd's into out.
// No fences, no second kernel, no partials buffer. R3 lesson: device-scope
// __threadfence serializes the whole kernel (57 us) — never again.
// d_out is zeroed by a capturable hipMemsetAsync before the kernel.
// ---------------------------------------------------------------------------

__global__ __launch_bounds__(256) void fused_atomic_kernel(
    const float* __restrict__ x, const float* __restrict__ Wv,
    const float* __restrict__ bv, float* __restrict__ out) {
    const int blk   = blockIdx.x;
    const int b     = blk >> 4;   // batch
    const int split = blk & 15;   // 64-row slice
    const int tid   = threadIdx.x;
    const int h4    = tid & 63;   // float4 column group (64 cover 256 floats)
    const int ph    = tid >> 6;   // 0..3 row phase

    // ---- Phase 1: partial column sum of 64 rows of x[b] ----
    const float4* xb = reinterpret_cast<const float4*>(
        x + (size_t)b * SS * HH + (size_t)split * ROWS * HH);

    float4 acc = make_float4(0.f, 0.f, 0.f, 0.f);
    #pragma unroll
    for (int r = ph; r < ROWS; r += 4) {
        float4 v = xb[(size_t)r * (HH / 4) + h4];
        acc.x += v.x; acc.y += v.y; acc.z += v.z; acc.w += v.w;
    }

    __shared__ float4 lds[256];
    __shared__ float xsum[HH];
    lds[tid] = acc;
    __syncthreads();
    if (tid < 64) {
        float4 a0 = lds[tid];
        float4 a1 = lds[tid + 64];
        float4 a2 = lds[tid + 128];
        float4 a3 = lds[tid + 192];
        float4 r;
        r.x = (a0.x + a1.x) + (a2.x + a3.x);
        r.y = (a0.y + a1.y) + (a2.y + a3.y);
        r.z = (a0.z + a1.z) + (a2.z + a3.z);
        r.w = (a0.w + a1.w) + (a2.w + a3.w);
        reinterpret_cast<float4*>(xsum)[tid] = r;
    }
    __syncthreads();

    // ---- Phase 2: matvec of THIS block's partial against Wv, atomic out ----
    const int h = tid;
    const float4* wrow = reinterpret_cast<const float4*>(Wv + (size_t)h * HH);
    const float4* xs   = reinterpret_cast<const float4*>(xsum);
    float o = (split == 0) ? (float)SS * bv[h] : 0.f;
    #pragma unroll 8
    for (int i = 0; i < HH / 4; ++i) {
        float4 w  = wrow[i];
        float4 xv = xs[i];
        o += w.x * xv.x + w.y * xv.y + w.z * xv.z + w.w * xv.w;
    }
    atomicAdd(&out[(size_t)b * HH + h], o);
}

extern "C" void kernel_launch(void* const* d_in, const int* in_sizes, int n_in,
                              void* d_out, int out_size, void* d_ws, size_t ws_size,
                              hipStream_t stream) {
    // setup_inputs order: x, Wq, bq, Wk, bk, Wv, bv
    const float* x  = (const float*)d_in[0];
    const float* Wv = (const float*)d_in[5];
    const float* bv = (const float*)d_in[6];
    float* out = (float*)d_out;

    // out must start at 0 every call (atomic accumulation target).
    hipMemsetAsync(out, 0, (size_t)BB * HH * sizeof(float), stream);

    fused_atomic_kernel<<<BB * SPLITS, 256, 0, stream>>>(x, Wv, bv, out);
}

// Round 5
// 23.869 us; speedup vs baseline: 2.2249x; 1.2611x over previous
//
#include <hip/hip_runtime.h>

// Problem constants (from reference): x[B,S,H], W*[H,H], b*[H], out[B,H]
#define BB 32
#define SS 1024
#define HH 256

// ---------------------------------------------------------------------------
// Math note: reference softmaxes over the QUERY axis (axis=1), so
// sum_q attn[b,q,k] == 1 for every (b,k). Then sum_q context = sum_k v.
// Hence out[b,h] = sum_h' Wv[h,h'] * (sum_s x[b,s,h']) + S * bv[h], exactly.
// Only x needs to be read (32 MB); Wq/bq/Wk/bk are provably unused.
//
// Structure (R5): ONE kernel node, ONE block per batch (32 blocks x 1024
// threads). No second kernel, no memset, no atomics, no fences — R3 showed
// device-scope fences serialize (57 us), R4 showed memset+atomics cost more
// than they save (30 us). Input is L3-resident on timed replays (R3 FETCH
// ~0.6 MB), so wall time is node overhead + per-CU streaming, not HBM BW.
// ---------------------------------------------------------------------------

__global__ __launch_bounds__(1024) void fused_batch_kernel(
    const float* __restrict__ x, const float* __restrict__ Wv,
    const float* __restrict__ bv, float* __restrict__ out) {
    const int b   = blockIdx.x;    // one batch per block
    const int tid = threadIdx.x;   // 0..1023
    const int h4  = tid & 63;      // float4 column group (64 cover 256 floats)
    const int ph  = tid >> 6;      // 0..15 row phase (one per wave)

    // ---- Phase 1: column sum of x[b] (1 MB), 64 float4 loads per thread ----
    const float4* xb = reinterpret_cast<const float4*>(x + (size_t)b * SS * HH);

    float4 acc = make_float4(0.f, 0.f, 0.f, 0.f);
    #pragma unroll 8
    for (int r = ph; r < SS; r += 16) {
        float4 v = xb[(size_t)r * (HH / 4) + h4];
        acc.x += v.x; acc.y += v.y; acc.z += v.z; acc.w += v.w;
    }

    // ---- LDS tree reduce over the 16 row phases (same h4 at +64 strides) ----
    __shared__ float4 lds[1024];
    __shared__ float xsum[HH];
    lds[tid] = acc;
    __syncthreads();
    if (tid < 512) {
        float4 a = lds[tid], c = lds[tid + 512];
        a.x += c.x; a.y += c.y; a.z += c.z; a.w += c.w;
        lds[tid] = a;
    }
    __syncthreads();
    if (tid < 256) {
        float4 a = lds[tid], c = lds[tid + 256];
        a.x += c.x; a.y += c.y; a.z += c.z; a.w += c.w;
        lds[tid] = a;
    }
    __syncthreads();
    if (tid < 128) {
        float4 a = lds[tid], c = lds[tid + 128];
        a.x += c.x; a.y += c.y; a.z += c.z; a.w += c.w;
        lds[tid] = a;
    }
    __syncthreads();
    if (tid < 64) {
        float4 a = lds[tid], c = lds[tid + 64];
        a.x += c.x; a.y += c.y; a.z += c.z; a.w += c.w;
        reinterpret_cast<float4*>(xsum)[tid] = a;
    }
    __syncthreads();

    // ---- Phase 2: out[b,h] = dot(Wv[h,:], xsum) + S*bv[h], threads 0..255 ----
    if (tid < HH) {
        const int h = tid;
        const float4* wrow = reinterpret_cast<const float4*>(Wv + (size_t)h * HH);
        const float4* xs   = reinterpret_cast<const float4*>(xsum);
        float o = (float)SS * bv[h];
        #pragma unroll 8
        for (int i = 0; i < HH / 4; ++i) {
            float4 w  = wrow[i];
            float4 xv = xs[i];
            o += w.x * xv.x + w.y * xv.y + w.z * xv.z + w.w * xv.w;
        }
        out[(size_t)b * HH + h] = o;
    }
}

extern "C" void kernel_launch(void* const* d_in, const int* in_sizes, int n_in,
                              void* d_out, int out_size, void* d_ws, size_t ws_size,
                              hipStream_t stream) {
    // setup_inputs order: x, Wq, bq, Wk, bk, Wv, bv
    const float* x  = (const float*)d_in[0];
    const float* Wv = (const float*)d_in[5];
    const float* bv = (const float*)d_in[6];
    float* out = (float*)d_out;

    fused_batch_kernel<<<BB, 1024, 0, stream>>>(x, Wv, bv, out);
}

// Round 6
// 15.616 us; speedup vs baseline: 3.4006x; 1.5285x over previous
//
#include <hip/hip_runtime.h>

// Problem constants (from reference): x[B,S,H], W*[H,H], b*[H], out[B,H]
#define BB 32
#define SS 1024
#define HH 256
#define SPLITS 16
#define ROWS (SS / SPLITS)  // 64 rows per A-block

// ---------------------------------------------------------------------------
// Math note: reference softmaxes over the QUERY axis (axis=1), so
// sum_q attn[b,q,k] == 1 for every (b,k). Then sum_q context = sum_k v.
// Hence out[b,h] = sum_h' Wv[h,h'] * (sum_s x[b,s,h']) + S * bv[h], exactly.
// Only x needs to be read (32 MB); Wq/bq/Wk/bk are provably unused.
//
// Structure lessons (R2-R5): streaming rate scales with ACTIVE CU COUNT
// (~44 GB/s/CU, miss-queue limited), not waves/CU -> phase 1 needs all 256
// CUs (512 blocks). Device fences serialize (R3: 57us). Atomics+memset cost
// more than a second node (R4: 30us). One-block-per-batch starves CUs
// (R5: 24us). So: 2 nodes, both wide.
// ---------------------------------------------------------------------------

// Kernel A: partial column sums of x over S. 512 blocks x 256 thr, all CUs.
// partials layout: [BB][SPLITS][HH] f32 (512 KB in d_ws).
__global__ __launch_bounds__(256) void xsum_partial_kernel(
    const float* __restrict__ x, float* __restrict__ partials) {
    const int blk   = blockIdx.x;
    const int b     = blk >> 4;
    const int split = blk & 15;
    const int tid   = threadIdx.x;
    const int h4    = tid & 63;   // float4 column group (64 cover 256 floats)
    const int ph    = tid >> 6;   // 0..3 row phase

    const float4* xb = reinterpret_cast<const float4*>(
        x + (size_t)b * SS * HH + (size_t)split * ROWS * HH);

    float4 acc = make_float4(0.f, 0.f, 0.f, 0.f);
    #pragma unroll
    for (int r = ph; r < ROWS; r += 4) {  // 16 independent loads in flight
        float4 v = xb[(size_t)r * (HH / 4) + h4];
        acc.x += v.x; acc.y += v.y; acc.z += v.z; acc.w += v.w;
    }

    __shared__ float4 lds[256];
    lds[tid] = acc;
    __syncthreads();
    if (tid < 64) {
        float4 a0 = lds[tid];
        float4 a1 = lds[tid + 64];
        float4 a2 = lds[tid + 128];
        float4 a3 = lds[tid + 192];
        float4 r;
        r.x = (a0.x + a1.x) + (a2.x + a3.x);
        r.y = (a0.y + a1.y) + (a2.y + a3.y);
        r.z = (a0.z + a1.z) + (a2.z + a3.z);
        r.w = (a0.w + a1.w) + (a2.w + a3.w);
        reinterpret_cast<float4*>(
            partials + ((size_t)b * SPLITS + split) * HH)[h4] = r;
    }
}

// Kernel B: 256 blocks x 256 thr (one per (batch, 32-h chunk), all CUs).
// Each block: reduce this batch's 16 partials -> xsum[256] in LDS (4 loads/
// thread), then 32 outputs via 8-lane-split dot + __shfl_xor reduce.
__global__ __launch_bounds__(256) void out_kernel(
    const float* __restrict__ partials, const float* __restrict__ Wv,
    const float* __restrict__ bv, float* __restrict__ out) {
    const int blk = blockIdx.x;
    const int b   = blk >> 3;          // batch
    const int hc  = (blk & 7) * 32;    // h-chunk base
    const int tid = threadIdx.x;

    // ---- reduce partials[b][16][256] -> xsum ----
    const int g  = tid & 63;   // float4 group
    const int sp = tid >> 6;   // 0..3 split phase
    const float4* pb = reinterpret_cast<const float4*>(
        partials + (size_t)b * SPLITS * HH);

    float4 a4 = make_float4(0.f, 0.f, 0.f, 0.f);
    #pragma unroll
    for (int c = sp; c < SPLITS; c += 4) {
        float4 v = pb[(size_t)c * (HH / 4) + g];
        a4.x += v.x; a4.y += v.y; a4.z += v.z; a4.w += v.w;
    }

    __shared__ float4 lds[256];
    __shared__ float xsum[HH];
    lds[tid] = a4;
    __syncthreads();
    if (tid < 64) {
        float4 a0 = lds[tid];
        float4 a1 = lds[tid + 64];
        float4 a2 = lds[tid + 128];
        float4 a3 = lds[tid + 192];
        float4 r;
        r.x = (a0.x + a1.x) + (a2.x + a3.x);
        r.y = (a0.y + a1.y) + (a2.y + a3.y);
        r.z = (a0.z + a1.z) + (a2.z + a3.z);
        r.w = (a0.w + a1.w) + (a2.w + a3.w);
        reinterpret_cast<float4*>(xsum)[tid] = r;
    }
    __syncthreads();

    // ---- dot: h = hc + (tid>>3), 8 lanes (seg=tid&7) split the 256-dot ----
    const int h   = hc + (tid >> 3);
    const int seg = tid & 7;           // 32-element segment
    const float4* wrow = reinterpret_cast<const float4*>(
        Wv + (size_t)h * HH + (size_t)seg * 32);
    const float4* xs = reinterpret_cast<const float4*>(xsum + (size_t)seg * 32);

    float o = 0.f;
    #pragma unroll
    for (int i = 0; i < 8; ++i) {      // 8 float4 = 32 MACs
        float4 w  = wrow[i];
        float4 xv = xs[i];
        o += w.x * xv.x + w.y * xv.y + w.z * xv.z + w.w * xv.w;
    }
    // reduce across the 8 segment lanes (consecutive lanes, same wave)
    o += __shfl_xor(o, 1);
    o += __shfl_xor(o, 2);
    o += __shfl_xor(o, 4);
    if (seg == 0)
        out[(size_t)b * HH + h] = o + (float)SS * bv[h];
}

extern "C" void kernel_launch(void* const* d_in, const int* in_sizes, int n_in,
                              void* d_out, int out_size, void* d_ws, size_t ws_size,
                              hipStream_t stream) {
    // setup_inputs order: x, Wq, bq, Wk, bk, Wv, bv
    const float* x  = (const float*)d_in[0];
    const float* Wv = (const float*)d_in[5];
    const float* bv = (const float*)d_in[6];
    float* out = (float*)d_out;
    float* partials = (float*)d_ws;  // BB*SPLITS*HH f32 = 512 KB

    xsum_partial_kernel<<<BB * SPLITS, 256, 0, stream>>>(x, partials);
    out_kernel<<<BB * 8, 256, 0, stream>>>(partials, Wv, bv, out);
}